// Round 2
// baseline (165.994 us; speedup 1.0000x reference)
//
#include <hip/hip_runtime.h>

#define HID 128
#define NN  256
#define BB  8
#define NCATS 64

// ---------------------------------------------------------------------------
// bf16 pack/unpack (RNE rounding on pack)
__device__ inline unsigned pack_bf16(float lo, float hi) {
    unsigned ul = __float_as_uint(lo);
    unsigned uh = __float_as_uint(hi);
    ul = (ul + 0x7fffu + ((ul >> 16) & 1u)) >> 16;
    uh = (uh + 0x7fffu + ((uh >> 16) & 1u)) & 0xffff0000u;
    return ul | uh;
}
__device__ inline float bf_lo(unsigned v) { return __uint_as_float(v << 16); }
__device__ inline float bf_hi(unsigned v) { return __uint_as_float(v & 0xffff0000u); }

// Wave-per-row LN reduction helper (row values a (lane), c (lane+64)).
__device__ inline void ln_stats(float a, float c, float& mean, float& rs) {
    float s = a + c;
    float q = a * a + c * c;
    #pragma unroll
    for (int m = 32; m; m >>= 1) {
        s += __shfl_xor(s, m);
        q += __shfl_xor(q, m);
    }
    mean = s * (1.0f / 128.0f);
    float var = q * (1.0f / 128.0f) - mean * mean;
    rs = rsqrtf(var + 1e-5f);
}

// ---------------------------------------------------------------------------
// Setup kernel:
//   blocks [0,256):   input MLP, 8 rows each  -> h0  (GEMM2 via bf16-transposed LDS)
//   blocks [256,264): normalize emb -> nep (bf16-packed, pairs of dims)
//   blocks [264,296): pack edge_cat transposed -> catp[jb*256+i] (8 cats/entry)
__global__ __launch_bounds__(512) void k_setup(
    const float* __restrict__ x, const float* __restrict__ emb,
    const float* __restrict__ inW1, const float* __restrict__ inb1,
    const float* __restrict__ ing1, const float* __restrict__ inbt1,
    const float* __restrict__ inW2, const float* __restrict__ inb2,
    const float* __restrict__ ing2, const float* __restrict__ inbt2,
    const int* __restrict__ ecat,
    unsigned* __restrict__ nep, uint2* __restrict__ catp, float* __restrict__ h0)
{
    __shared__ __align__(16) float sV[8][128];
    __shared__ __align__(16) float sH1[8][128];
    __shared__ __align__(16) float sA[4][8][128];
    __shared__ __align__(16) uint4 sH1T[128];

    const int blk = blockIdx.x;
    const int t = threadIdx.x;
    const int w = t >> 6, lane = t & 63;

    if (blk < 256) {
        const int dd = t & 127, ks = t >> 7;
        // prefetch this thread's W2 column chunk while we do linear1/LN1
        float w2r[32];
        #pragma unroll
        for (int k = 0; k < 32; ++k) w2r[k] = inW2[(ks * 32 + k) * 128 + dd];

        const int row0 = blk * 8;
        // Linear(2->128): CIN=2 inline, no reduction
        for (int item = t; item < 1024; item += 512) {
            int r = item >> 7, d2 = item & 127;
            int row = row0 + r;
            float x0 = x[row * 2 + 0], x1 = x[row * 2 + 1];
            sV[r][d2] = fmaf(x0, inW1[d2], fmaf(x1, inW1[128 + d2], inb1[d2]));
        }
        __syncthreads();
        // LN1 + relu
        {
            float a = sV[w][lane], c = sV[w][lane + 64];
            float mean, rs; ln_stats(a, c, mean, rs);
            sH1[w][lane]      = fmaxf((a - mean) * rs * ing1[lane]      + inbt1[lane],      0.f);
            sH1[w][lane + 64] = fmaxf((c - mean) * rs * ing1[lane + 64] + inbt1[lane + 64], 0.f);
        }
        __syncthreads();
        // repack: sH1T[k].w[wr] = bf16(row 2wr, row 2wr+1) at dim k
        {
            int kd = t & 127, wr = t >> 7;
            ((unsigned*)sH1T)[kd * 4 + wr] = pack_bf16(sH1[2 * wr][kd], sH1[2 * wr + 1][kd]);
        }
        __syncthreads();
        // GEMM2 (128x128): k-split by 4, transposed bf16 A, prefetched W
        {
            float a8[8] = {0.f,0.f,0.f,0.f,0.f,0.f,0.f,0.f};
            #pragma unroll
            for (int k = 0; k < 32; ++k) {
                uint4 a = sH1T[ks * 32 + k];
                float wv = w2r[k];
                a8[0] = fmaf(bf_lo(a.x), wv, a8[0]);
                a8[1] = fmaf(bf_hi(a.x), wv, a8[1]);
                a8[2] = fmaf(bf_lo(a.y), wv, a8[2]);
                a8[3] = fmaf(bf_hi(a.y), wv, a8[3]);
                a8[4] = fmaf(bf_lo(a.z), wv, a8[4]);
                a8[5] = fmaf(bf_hi(a.z), wv, a8[5]);
                a8[6] = fmaf(bf_lo(a.w), wv, a8[6]);
                a8[7] = fmaf(bf_hi(a.w), wv, a8[7]);
            }
            #pragma unroll
            for (int r = 0; r < 8; ++r) sA[ks][r][dd] = a8[r];
        }
        __syncthreads();
        for (int item = t; item < 1024; item += 512) {
            int r = item >> 7, d2 = item & 127;
            sV[r][d2] = inb2[d2] + sA[0][r][d2] + sA[1][r][d2] + sA[2][r][d2] + sA[3][r][d2];
        }
        __syncthreads();
        // LN2 -> h0
        {
            float a = sV[w][lane], c = sV[w][lane + 64];
            float mean, rs; ln_stats(a, c, mean, rs);
            int row = row0 + w;
            h0[row * HID + lane]      = (a - mean) * rs * ing2[lane]      + inbt2[lane];
            h0[row * HID + lane + 64] = (c - mean) * rs * ing2[lane + 64] + inbt2[lane + 64];
        }
    } else if (blk < 264) {
        // normalize emb rows -> bf16-packed nep; lane owns dims (2*lane, 2*lane+1)
        int r = (blk - 256) * 8 + w;
        float2 em = *(const float2*)(emb + r * 128 + 2 * lane);
        float q = em.x * em.x + em.y * em.y;
        #pragma unroll
        for (int m = 32; m; m >>= 1) q += __shfl_xor(q, m);
        float cn = sqrtf(q);
        if (cn == 0.f) cn = 1e-8f;
        float sc = fminf(1.0f, 1.0f / cn);
        nep[r * 64 + lane] = pack_bf16(em.x * sc, em.y * sc);
    } else {
        // pack transposed categories: catp[jb*256+i] = cats of (i, jb*8 .. jb*8+7)
        int jb = blk - 264;
        if (t < 256) {
            int i = t;
            const int* p = ecat + i * NN + jb * 8;
            int4 c0 = *(const int4*)p;
            int4 c1 = *(const int4*)(p + 4);
            unsigned lo = (unsigned)c0.x | ((unsigned)c0.y << 8) |
                          ((unsigned)c0.z << 16) | ((unsigned)c0.w << 24);
            unsigned hi = (unsigned)c1.x | ((unsigned)c1.y << 8) |
                          ((unsigned)c1.z << 16) | ((unsigned)c1.w << 24);
            catp[jb * 256 + i] = make_uint2(lo, hi);
        }
    }
}

// ---------------------------------------------------------------------------
// One GINE layer, fused. bf16 ne in LDS; transposed bf16 GEMM staging;
// W columns prefetched to registers.
__global__ __launch_bounds__(512) void k_layer(
    const float* __restrict__ h_old, float* __restrict__ h_new,
    const uint4* __restrict__ nep4, const uint2* __restrict__ catp,
    const float* __restrict__ W1, const float* __restrict__ b1,
    const float* __restrict__ g1, const float* __restrict__ bt1,
    const float* __restrict__ W2, const float* __restrict__ b2,
    const float* __restrict__ g2, const float* __restrict__ bt2,
    const float* __restrict__ epsp,
    const float* __restrict__ lng, const float* __restrict__ lnb,
    const float* __restrict__ outW, const float* __restrict__ outb,
    float* __restrict__ dout, int isLast)
{
    __shared__ __align__(16) uint4 sNe4[NCATS * 16];    // 16 KB bf16-packed ne
    __shared__ __align__(16) float sPart[16 * 8 * 128]; // 64 KB agg partials / GEMM partials
    __shared__ __align__(16) uint2 sCat[256];           // 2 KB
    __shared__ __align__(16) uint4 sUT[128];            // 2 KB  (u, transposed bf16)
    __shared__ __align__(16) float sH1[8][128];         // 4 KB
    __shared__ __align__(16) uint4 sH1T[128];           // 2 KB  (h1, transposed bf16)
    __shared__ __align__(16) float sV[8][128];          // 4 KB

    const int t = threadIdx.x;
    const int b = blockIdx.x >> 5;
    const int jb = blockIdx.x & 31;
    const int w = t >> 6, lane = t & 63;
    const float* hb = h_old + (size_t)b * NN * HID;
    const uint2* sNe2 = (const uint2*)sNe4;

    // stage bf16 ne (1024 uint4) + this block's packed cats
    for (int idx = t; idx < 1024; idx += 512) sNe4[idx] = nep4[idx];
    if (t < 256) sCat[t] = catp[jb * 256 + t];
    __syncthreads();

    // ---- aggregation: agg[j][d] = sum_i relu(h[i][d] + ne[cat(i,j)][d]) ----
    // thread owns 4 dims (dg) x 16 sources (ig); accumulates 8 dst j in regs
    const int dg = t & 31;   // dims [dg*4, dg*4+4)
    const int ig = t >> 5;   // i in [ig*16, ig*16+16)
    float4 hv[16];
    #pragma unroll
    for (int n = 0; n < 16; ++n)
        hv[n] = *(const float4*)(hb + (ig * 16 + n) * HID + dg * 4);

    float acc[8][4];
    #pragma unroll
    for (int k = 0; k < 8; ++k)
        #pragma unroll
        for (int d = 0; d < 4; ++d) acc[k][d] = 0.f;

    #pragma unroll
    for (int n = 0; n < 16; ++n) {
        uint2 c8 = sCat[ig * 16 + n];
        float hx = hv[n].x, hy = hv[n].y, hz = hv[n].z, hw = hv[n].w;
        #pragma unroll
        for (int k = 0; k < 8; ++k) {
            unsigned c = ((k < 4 ? (c8.x >> (8 * k)) : (c8.y >> (8 * (k - 4)))) & 255u);
            uint2 nv = sNe2[c * 32 + dg];
            acc[k][0] += fmaxf(hx + bf_lo(nv.x), 0.f);
            acc[k][1] += fmaxf(hy + bf_hi(nv.x), 0.f);
            acc[k][2] += fmaxf(hz + bf_lo(nv.y), 0.f);
            acc[k][3] += fmaxf(hw + bf_hi(nv.y), 0.f);
        }
    }
    #pragma unroll
    for (int k = 0; k < 8; ++k)
        *(float4*)&sPart[(ig * 8 + k) * 128 + dg * 4] =
            make_float4(acc[k][0], acc[k][1], acc[k][2], acc[k][3]);

    // prefetch W1/W2 column chunks (latency hides under combine phase)
    const int dd = t & 127, ks = t >> 7;
    float w1r[32], w2r[32];
    #pragma unroll
    for (int k = 0; k < 32; ++k) w1r[k] = W1[(ks * 32 + k) * 128 + dd];
    #pragma unroll
    for (int k = 0; k < 32; ++k) w2r[k] = W2[(ks * 32 + k) * 128 + dd];
    __syncthreads();

    // ---- combine partials, u = (1+eps)*h + agg; pack transposed bf16 ----
    {
        const int kd = t & 127, wr = t >> 7;   // rows 2wr, 2wr+1 at dim kd
        const float eps1 = 1.0f + epsp[0];
        float u0 = eps1 * hb[(jb * 8 + 2 * wr) * HID + kd];
        float u1 = eps1 * hb[(jb * 8 + 2 * wr + 1) * HID + kd];
        #pragma unroll
        for (int g = 0; g < 16; ++g) {
            u0 += sPart[(g * 8 + 2 * wr) * 128 + kd];
            u1 += sPart[(g * 8 + 2 * wr + 1) * 128 + kd];
        }
        ((unsigned*)sUT)[kd * 4 + wr] = pack_bf16(u0, u1);
    }
    __syncthreads();

    // ---- GEMM1: v = u @ W1 (transposed bf16 A, broadcast b128 reads) ----
    {
        float a8[8] = {0.f,0.f,0.f,0.f,0.f,0.f,0.f,0.f};
        #pragma unroll
        for (int k = 0; k < 32; ++k) {
            uint4 a = sUT[ks * 32 + k];
            float wv = w1r[k];
            a8[0] = fmaf(bf_lo(a.x), wv, a8[0]);
            a8[1] = fmaf(bf_hi(a.x), wv, a8[1]);
            a8[2] = fmaf(bf_lo(a.y), wv, a8[2]);
            a8[3] = fmaf(bf_hi(a.y), wv, a8[3]);
            a8[4] = fmaf(bf_lo(a.z), wv, a8[4]);
            a8[5] = fmaf(bf_hi(a.z), wv, a8[5]);
            a8[6] = fmaf(bf_lo(a.w), wv, a8[6]);
            a8[7] = fmaf(bf_hi(a.w), wv, a8[7]);
        }
        #pragma unroll
        for (int r = 0; r < 8; ++r) sPart[(ks * 8 + r) * 128 + dd] = a8[r];
    }
    __syncthreads();
    for (int item = t; item < 1024; item += 512) {
        int r = item >> 7, d2 = item & 127;
        sV[r][d2] = b1[d2] + sPart[r * 128 + d2] + sPart[(8 + r) * 128 + d2] +
                    sPart[(16 + r) * 128 + d2] + sPart[(24 + r) * 128 + d2];
    }
    __syncthreads();

    // ---- LN1 + relu -> sH1 ----
    {
        float a = sV[w][lane], c = sV[w][lane + 64];
        float mean, rs; ln_stats(a, c, mean, rs);
        sH1[w][lane]      = fmaxf((a - mean) * rs * g1[lane]      + bt1[lane],      0.f);
        sH1[w][lane + 64] = fmaxf((c - mean) * rs * g1[lane + 64] + bt1[lane + 64], 0.f);
    }
    __syncthreads();
    // repack transposed bf16
    {
        const int kd = t & 127, wr = t >> 7;
        ((unsigned*)sH1T)[kd * 4 + wr] = pack_bf16(sH1[2 * wr][kd], sH1[2 * wr + 1][kd]);
    }
    __syncthreads();

    // ---- GEMM2: v = h1 @ W2 ----
    {
        float a8[8] = {0.f,0.f,0.f,0.f,0.f,0.f,0.f,0.f};
        #pragma unroll
        for (int k = 0; k < 32; ++k) {
            uint4 a = sH1T[ks * 32 + k];
            float wv = w2r[k];
            a8[0] = fmaf(bf_lo(a.x), wv, a8[0]);
            a8[1] = fmaf(bf_hi(a.x), wv, a8[1]);
            a8[2] = fmaf(bf_lo(a.y), wv, a8[2]);
            a8[3] = fmaf(bf_hi(a.y), wv, a8[3]);
            a8[4] = fmaf(bf_lo(a.z), wv, a8[4]);
            a8[5] = fmaf(bf_hi(a.z), wv, a8[5]);
            a8[6] = fmaf(bf_lo(a.w), wv, a8[6]);
            a8[7] = fmaf(bf_hi(a.w), wv, a8[7]);
        }
        #pragma unroll
        for (int r = 0; r < 8; ++r) sPart[(ks * 8 + r) * 128 + dd] = a8[r];
    }
    __syncthreads();
    for (int item = t; item < 1024; item += 512) {
        int r = item >> 7, d2 = item & 127;
        sV[r][d2] = b2[d2] + sPart[r * 128 + d2] + sPart[(8 + r) * 128 + d2] +
                    sPart[(16 + r) * 128 + d2] + sPart[(24 + r) * 128 + d2];
    }
    __syncthreads();

    // ---- LN2 (g2,bt2) then LN3 (lng,lnb) + relu + residual ----
    {
        float a = sV[w][lane], c = sV[w][lane + 64];
        float mean, rs; ln_stats(a, c, mean, rs);
        float y1 = (a - mean) * rs * g2[lane]      + bt2[lane];
        float y2 = (c - mean) * rs * g2[lane + 64] + bt2[lane + 64];

        float mean3, rs3; ln_stats(y1, y2, mean3, rs3);
        int row = jb * 8 + w;
        int grow = b * NN + row;
        float ho1 = hb[row * HID + lane], ho2 = hb[row * HID + lane + 64];
        float z1 = fmaxf((y1 - mean3) * rs3 * lng[lane]      + lnb[lane],      0.f) + ho1;
        float z2 = fmaxf((y2 - mean3) * rs3 * lng[lane + 64] + lnb[lane + 64], 0.f) + ho2;

        if (!isLast) {
            h_new[(size_t)grow * HID + lane]      = z1;
            h_new[(size_t)grow * HID + lane + 64] = z2;
        } else {
            #pragma unroll
            for (int cc = 0; cc < 3; ++cc) {
                float p = z1 * outW[lane * 3 + cc] + z2 * outW[(lane + 64) * 3 + cc];
                #pragma unroll
                for (int m = 32; m; m >>= 1) p += __shfl_xor(p, m);
                if (lane == 0) dout[grow * 3 + cc] = p + outb[cc];
            }
        }
    }
}

// ---------------------------------------------------------------------------
extern "C" void kernel_launch(void* const* d_in, const int* in_sizes, int n_in,
                              void* d_out, int out_size, void* d_ws, size_t ws_size,
                              hipStream_t stream) {
    const float* x     = (const float*)d_in[0];
    const float* emb   = (const float*)d_in[1];
    const float* inW1  = (const float*)d_in[2];
    const float* inb1  = (const float*)d_in[3];
    const float* ing1  = (const float*)d_in[4];
    const float* inbt1 = (const float*)d_in[5];
    const float* inW2  = (const float*)d_in[6];
    const float* inb2  = (const float*)d_in[7];
    const float* ing2  = (const float*)d_in[8];
    const float* inbt2 = (const float*)d_in[9];
    const float* cW1   = (const float*)d_in[10];
    const float* cb1   = (const float*)d_in[11];
    const float* cg1   = (const float*)d_in[12];
    const float* cbt1  = (const float*)d_in[13];
    const float* cW2   = (const float*)d_in[14];
    const float* cb2   = (const float*)d_in[15];
    const float* cg2   = (const float*)d_in[16];
    const float* cbt2  = (const float*)d_in[17];
    const float* ceps  = (const float*)d_in[18];
    const float* lng   = (const float*)d_in[19];
    const float* lnb   = (const float*)d_in[20];
    const float* outW  = (const float*)d_in[21];
    const float* outb  = (const float*)d_in[22];
    const int*   ecat  = (const int*)d_in[25];

    float* ws   = (float*)d_ws;
    unsigned* nep = (unsigned*)ws;              // 4096 u32 (16 KB bf16 ne)
    uint2* catp = (uint2*)(ws + 4096);          // 8192 uint2
    float* hA   = ws + 4096 + 16384;            // B*N*HID
    float* hB   = hA + BB * NN * HID;
    float* out  = (float*)d_out;

    k_setup<<<296, 512, 0, stream>>>(x, emb, inW1, inb1, ing1, inbt1,
                                     inW2, inb2, ing2, inbt2, ecat, nep, catp, hA);

    for (int l = 0; l < 4; ++l) {
        const float* ho = (l & 1) ? hB : hA;
        float*       hn = (l & 1) ? hA : hB;
        k_layer<<<256, 512, 0, stream>>>(
            ho, hn, (const uint4*)nep, catp,
            cW1 + l * HID * HID, cb1 + l * HID, cg1 + l * HID, cbt1 + l * HID,
            cW2 + l * HID * HID, cb2 + l * HID, cg2 + l * HID, cbt2 + l * HID,
            ceps + l, lng + l * HID, lnb + l * HID,
            outW, outb, out, (l == 3) ? 1 : 0);
    }
}

// Round 3
// 111.013 us; speedup vs baseline: 1.4953x; 1.4953x over previous
//
#include <hip/hip_runtime.h>

#define HID 128
#define NN  256
#define BB  8
#define NCATS 64

// ---------------------------------------------------------------------------
// bf16 pack/unpack (RNE rounding on pack)
__device__ inline unsigned pack_bf16(float lo, float hi) {
    unsigned ul = __float_as_uint(lo);
    unsigned uh = __float_as_uint(hi);
    ul = (ul + 0x7fffu + ((ul >> 16) & 1u)) >> 16;
    uh = (uh + 0x7fffu + ((uh >> 16) & 1u)) & 0xffff0000u;
    return ul | uh;
}
__device__ inline float bf_lo(unsigned v) { return __uint_as_float(v << 16); }
__device__ inline float bf_hi(unsigned v) { return __uint_as_float(v & 0xffff0000u); }

// Wave-per-row LN reduction helper (row values a (lane), c (lane+64)).
__device__ inline void ln_stats(float a, float c, float& mean, float& rs) {
    float s = a + c;
    float q = a * a + c * c;
    #pragma unroll
    for (int m = 32; m; m >>= 1) {
        s += __shfl_xor(s, m);
        q += __shfl_xor(q, m);
    }
    mean = s * (1.0f / 128.0f);
    float var = q * (1.0f / 128.0f) - mean * mean;
    rs = rsqrtf(var + 1e-5f);
}

// ---------------------------------------------------------------------------
// Setup kernel:
//   blocks [0,256):   input MLP, 8 rows each  -> h0
//   blocks [256,264): normalize emb -> nep (bf16-packed, pairs of dims)
//   blocks [264,328): pack edge_cat: catp[jg*256+i] = cats of (i, jg*4..jg*4+3)
__global__ __launch_bounds__(512) void k_setup(
    const float* __restrict__ x, const float* __restrict__ emb,
    const float* __restrict__ inW1, const float* __restrict__ inb1,
    const float* __restrict__ ing1, const float* __restrict__ inbt1,
    const float* __restrict__ inW2, const float* __restrict__ inb2,
    const float* __restrict__ ing2, const float* __restrict__ inbt2,
    const int* __restrict__ ecat,
    unsigned* __restrict__ nep, unsigned* __restrict__ catp, float* __restrict__ h0)
{
    __shared__ __align__(16) float sV[8][128];
    __shared__ __align__(16) float sH1[8][128];
    __shared__ __align__(16) float sA[4][8][128];
    __shared__ __align__(16) uint4 sH1T[128];

    const int blk = blockIdx.x;
    const int t = threadIdx.x;
    const int w = t >> 6, lane = t & 63;

    if (blk < 256) {
        const int row0 = blk * 8;
        // Linear(2->128): CIN=2 inline, no reduction
        for (int item = t; item < 1024; item += 512) {
            int r = item >> 7, d2 = item & 127;
            int row = row0 + r;
            float x0 = x[row * 2 + 0], x1 = x[row * 2 + 1];
            sV[r][d2] = fmaf(x0, inW1[d2], fmaf(x1, inW1[128 + d2], inb1[d2]));
        }
        __syncthreads();
        // LN1 + relu
        {
            float a = sV[w][lane], c = sV[w][lane + 64];
            float mean, rs; ln_stats(a, c, mean, rs);
            sH1[w][lane]      = fmaxf((a - mean) * rs * ing1[lane]      + inbt1[lane],      0.f);
            sH1[w][lane + 64] = fmaxf((c - mean) * rs * ing1[lane + 64] + inbt1[lane + 64], 0.f);
        }
        __syncthreads();
        // repack transposed bf16: sH1T[k].comp[wr] = bf16(row 2wr, 2wr+1) at dim k
        {
            int kd = t & 127, wr = t >> 7;
            ((unsigned*)sH1T)[kd * 4 + wr] = pack_bf16(sH1[2 * wr][kd], sH1[2 * wr + 1][kd]);
        }
        __syncthreads();
        // GEMM2 (128x128): k-split by 4, inline W loads (no reg prefetch)
        {
            const int dd = t & 127, ks = t >> 7;
            float a8[8] = {0.f,0.f,0.f,0.f,0.f,0.f,0.f,0.f};
            #pragma unroll 8
            for (int k = 0; k < 32; ++k) {
                int kk = ks * 32 + k;
                uint4 a = sH1T[kk];
                float wv = inW2[kk * 128 + dd];
                a8[0] = fmaf(bf_lo(a.x), wv, a8[0]);
                a8[1] = fmaf(bf_hi(a.x), wv, a8[1]);
                a8[2] = fmaf(bf_lo(a.y), wv, a8[2]);
                a8[3] = fmaf(bf_hi(a.y), wv, a8[3]);
                a8[4] = fmaf(bf_lo(a.z), wv, a8[4]);
                a8[5] = fmaf(bf_hi(a.z), wv, a8[5]);
                a8[6] = fmaf(bf_lo(a.w), wv, a8[6]);
                a8[7] = fmaf(bf_hi(a.w), wv, a8[7]);
            }
            #pragma unroll
            for (int r = 0; r < 8; ++r) sA[ks][r][dd] = a8[r];
        }
        __syncthreads();
        for (int item = t; item < 1024; item += 512) {
            int r = item >> 7, d2 = item & 127;
            sV[r][d2] = inb2[d2] + sA[0][r][d2] + sA[1][r][d2] + sA[2][r][d2] + sA[3][r][d2];
        }
        __syncthreads();
        // LN2 -> h0
        {
            float a = sV[w][lane], c = sV[w][lane + 64];
            float mean, rs; ln_stats(a, c, mean, rs);
            int row = row0 + w;
            h0[row * HID + lane]      = (a - mean) * rs * ing2[lane]      + inbt2[lane];
            h0[row * HID + lane + 64] = (c - mean) * rs * ing2[lane + 64] + inbt2[lane + 64];
        }
    } else if (blk < 264) {
        // normalize emb rows -> bf16-packed nep; lane owns dims (2*lane, 2*lane+1)
        int r = (blk - 256) * 8 + w;
        float2 em = *(const float2*)(emb + r * 128 + 2 * lane);
        float q = em.x * em.x + em.y * em.y;
        #pragma unroll
        for (int m = 32; m; m >>= 1) q += __shfl_xor(q, m);
        float cn = sqrtf(q);
        if (cn == 0.f) cn = 1e-8f;
        float sc = fminf(1.0f, 1.0f / cn);
        nep[r * 64 + lane] = pack_bf16(em.x * sc, em.y * sc);
    } else {
        // pack cats: catp[jg*256+i] = u32 of cats (i, jg*4 .. jg*4+3)
        int jg = blk - 264;
        if (t < 256) {
            int i = t;
            int4 c = *(const int4*)(ecat + i * NN + jg * 4);
            catp[jg * 256 + i] = (unsigned)c.x | ((unsigned)c.y << 8) |
                                 ((unsigned)c.z << 16) | ((unsigned)c.w << 24);
        }
    }
}

// ---------------------------------------------------------------------------
// One GINE layer, fused. 4 destination rows per block, grid = B * 64 = 512.
// bf16 ne in LDS (uint4 = 8 dims); in-wave xor-16 pre-reduction of agg
// partials; transposed-bf16 GEMM staging; all W loads inline (no prefetch).
__global__ __launch_bounds__(512, 4) void k_layer(
    const float* __restrict__ h_old, float* __restrict__ h_new,
    const uint4* __restrict__ nep4, const unsigned* __restrict__ catp,
    const float* __restrict__ W1, const float* __restrict__ b1,
    const float* __restrict__ g1, const float* __restrict__ bt1,
    const float* __restrict__ W2, const float* __restrict__ b2,
    const float* __restrict__ g2, const float* __restrict__ bt2,
    const float* __restrict__ epsp,
    const float* __restrict__ lng, const float* __restrict__ lnb,
    const float* __restrict__ outW, const float* __restrict__ outb,
    float* __restrict__ dout, int isLast)
{
    __shared__ __align__(16) uint4    sNe4[NCATS * 16];    // 16 KB bf16 ne
    __shared__ __align__(16) float    sPart[16 * 4 * 128]; // 32 KB agg/GEMM partials
    __shared__ __align__(16) unsigned sCat[256];           // 1 KB
    __shared__ __align__(16) uint2    sUT[128];            // 1 KB (u transposed bf16)
    __shared__ __align__(16) float    sH1[4][128];         // 2 KB
    __shared__ __align__(16) uint2    sH1T[128];           // 1 KB
    __shared__ __align__(16) float    sV[4][128];          // 2 KB

    const int t  = threadIdx.x;
    const int b  = blockIdx.x >> 6;
    const int jg = blockIdx.x & 63;
    const float* hb = h_old + (size_t)b * NN * HID;

    // stage bf16 ne (1024 uint4) + this block's packed cats
    for (int idx = t; idx < 1024; idx += 512) sNe4[idx] = nep4[idx];
    if (t < 256) sCat[t] = catp[jg * 256 + t];
    __syncthreads();

    // ---- aggregation: agg[j][d] = sum_i relu(h[i][d] + ne[cat(i,j)][d]) ----
    // thread: dims [dg*8, dg*8+8), sources [ig*8, ig*8+8), 4 dst in regs
    const int dg = t & 15;
    const int ig = t >> 4;
    float acc[4][8];
    #pragma unroll
    for (int k = 0; k < 4; ++k)
        #pragma unroll
        for (int d = 0; d < 8; ++d) acc[k][d] = 0.f;

    #pragma unroll 2
    for (int n = 0; n < 8; ++n) {
        int i = ig * 8 + n;
        const float* hp = hb + i * HID + dg * 8;
        float4 h0 = *(const float4*)hp;
        float4 h1 = *(const float4*)(hp + 4);
        unsigned c4 = sCat[i];
        #pragma unroll
        for (int k = 0; k < 4; ++k) {
            unsigned c = (c4 >> (8 * k)) & 255u;
            uint4 nv = sNe4[c * 16 + dg];
            acc[k][0] += fmaxf(h0.x + bf_lo(nv.x), 0.f);
            acc[k][1] += fmaxf(h0.y + bf_hi(nv.x), 0.f);
            acc[k][2] += fmaxf(h0.z + bf_lo(nv.y), 0.f);
            acc[k][3] += fmaxf(h0.w + bf_hi(nv.y), 0.f);
            acc[k][4] += fmaxf(h1.x + bf_lo(nv.z), 0.f);
            acc[k][5] += fmaxf(h1.y + bf_hi(nv.z), 0.f);
            acc[k][6] += fmaxf(h1.z + bf_lo(nv.w), 0.f);
            acc[k][7] += fmaxf(h1.w + bf_hi(nv.w), 0.f);
        }
    }
    // in-wave pre-reduction: combine subgroup pairs (lane ^ 16)
    #pragma unroll
    for (int k = 0; k < 4; ++k)
        #pragma unroll
        for (int d = 0; d < 8; ++d)
            acc[k][d] += __shfl_xor(acc[k][d], 16);
    // write partials: pg = wave*2 + (s>>1); lane-subgroup parity picks dst pair
    {
        int wv = t >> 6;
        int s  = (t >> 4) & 3;
        int pg = wv * 2 + (s >> 1);
        int kp = (s & 1) * 2;   // this lane writes dst kp, kp+1
        float* p0 = &sPart[(pg * 4 + kp) * 128 + dg * 8];
        float* p1 = p0 + 128;
        *(float4*)(p0)     = make_float4(acc[kp][0], acc[kp][1], acc[kp][2], acc[kp][3]);
        *(float4*)(p0 + 4) = make_float4(acc[kp][4], acc[kp][5], acc[kp][6], acc[kp][7]);
        *(float4*)(p1)     = make_float4(acc[kp+1][0], acc[kp+1][1], acc[kp+1][2], acc[kp+1][3]);
        *(float4*)(p1 + 4) = make_float4(acc[kp+1][4], acc[kp+1][5], acc[kp+1][6], acc[kp+1][7]);
    }
    __syncthreads();

    // ---- combine partials, u = (1+eps)*h + agg; pack transposed bf16 ----
    if (t < 256) {
        int dim = t & 127, p = t >> 7;     // rows 2p, 2p+1
        const float eps1 = 1.0f + epsp[0];
        int r0 = 2 * p, r1 = 2 * p + 1;
        float u0 = eps1 * hb[(jg * 4 + r0) * HID + dim];
        float u1 = eps1 * hb[(jg * 4 + r1) * HID + dim];
        #pragma unroll
        for (int pg = 0; pg < 16; ++pg) {
            u0 += sPart[(pg * 4 + r0) * 128 + dim];
            u1 += sPart[(pg * 4 + r1) * 128 + dim];
        }
        ((unsigned*)sUT)[dim * 2 + p] = pack_bf16(u0, u1);
    }
    __syncthreads();

    // ---- GEMM1: v = u @ W1 (transposed bf16 A, broadcast b64 reads) ----
    {
        const int dd = t & 127, ks = t >> 7;
        float a4[4] = {0.f, 0.f, 0.f, 0.f};
        #pragma unroll 8
        for (int k = 0; k < 32; ++k) {
            int kk = ks * 32 + k;
            uint2 aa = sUT[kk];
            float wv = W1[kk * 128 + dd];
            a4[0] = fmaf(bf_lo(aa.x), wv, a4[0]);
            a4[1] = fmaf(bf_hi(aa.x), wv, a4[1]);
            a4[2] = fmaf(bf_lo(aa.y), wv, a4[2]);
            a4[3] = fmaf(bf_hi(aa.y), wv, a4[3]);
        }
        #pragma unroll
        for (int r = 0; r < 4; ++r) sPart[(ks * 4 + r) * 128 + dd] = a4[r];
    }
    __syncthreads();
    {
        int r = t >> 7, dim = t & 127;
        sV[r][dim] = b1[dim] + sPart[r * 128 + dim] + sPart[(4 + r) * 128 + dim] +
                     sPart[(8 + r) * 128 + dim] + sPart[(12 + r) * 128 + dim];
    }
    __syncthreads();

    // ---- LN1 + relu -> sH1 ----
    if (t < 256) {
        int w = t >> 6, lane = t & 63;
        float a = sV[w][lane], c = sV[w][lane + 64];
        float mean, rs; ln_stats(a, c, mean, rs);
        sH1[w][lane]      = fmaxf((a - mean) * rs * g1[lane]      + bt1[lane],      0.f);
        sH1[w][lane + 64] = fmaxf((c - mean) * rs * g1[lane + 64] + bt1[lane + 64], 0.f);
    }
    __syncthreads();
    if (t < 256) {
        int dim = t & 127, p = t >> 7;
        ((unsigned*)sH1T)[dim * 2 + p] = pack_bf16(sH1[2 * p][dim], sH1[2 * p + 1][dim]);
    }
    __syncthreads();

    // ---- GEMM2: v = h1 @ W2 ----
    {
        const int dd = t & 127, ks = t >> 7;
        float a4[4] = {0.f, 0.f, 0.f, 0.f};
        #pragma unroll 8
        for (int k = 0; k < 32; ++k) {
            int kk = ks * 32 + k;
            uint2 aa = sH1T[kk];
            float wv = W2[kk * 128 + dd];
            a4[0] = fmaf(bf_lo(aa.x), wv, a4[0]);
            a4[1] = fmaf(bf_hi(aa.x), wv, a4[1]);
            a4[2] = fmaf(bf_lo(aa.y), wv, a4[2]);
            a4[3] = fmaf(bf_hi(aa.y), wv, a4[3]);
        }
        #pragma unroll
        for (int r = 0; r < 4; ++r) sPart[(ks * 4 + r) * 128 + dd] = a4[r];
    }
    __syncthreads();
    {
        int r = t >> 7, dim = t & 127;
        sV[r][dim] = b2[dim] + sPart[r * 128 + dim] + sPart[(4 + r) * 128 + dim] +
                     sPart[(8 + r) * 128 + dim] + sPart[(12 + r) * 128 + dim];
    }
    __syncthreads();

    // ---- LN2 (g2,bt2) then LN3 (lng,lnb) + relu + residual ----
    if (t < 256) {
        int w = t >> 6, lane = t & 63;
        float a = sV[w][lane], c = sV[w][lane + 64];
        float mean, rs; ln_stats(a, c, mean, rs);
        float y1 = (a - mean) * rs * g2[lane]      + bt2[lane];
        float y2 = (c - mean) * rs * g2[lane + 64] + bt2[lane + 64];

        float mean3, rs3; ln_stats(y1, y2, mean3, rs3);
        int row = jg * 4 + w;
        int grow = b * NN + row;
        float ho1 = hb[row * HID + lane], ho2 = hb[row * HID + lane + 64];
        float z1 = fmaxf((y1 - mean3) * rs3 * lng[lane]      + lnb[lane],      0.f) + ho1;
        float z2 = fmaxf((y2 - mean3) * rs3 * lng[lane + 64] + lnb[lane + 64], 0.f) + ho2;

        if (!isLast) {
            h_new[(size_t)grow * HID + lane]      = z1;
            h_new[(size_t)grow * HID + lane + 64] = z2;
        } else {
            #pragma unroll
            for (int cc = 0; cc < 3; ++cc) {
                float p = z1 * outW[lane * 3 + cc] + z2 * outW[(lane + 64) * 3 + cc];
                #pragma unroll
                for (int m = 32; m; m >>= 1) p += __shfl_xor(p, m);
                if (lane == 0) dout[grow * 3 + cc] = p + outb[cc];
            }
        }
    }
}

// ---------------------------------------------------------------------------
extern "C" void kernel_launch(void* const* d_in, const int* in_sizes, int n_in,
                              void* d_out, int out_size, void* d_ws, size_t ws_size,
                              hipStream_t stream) {
    const float* x     = (const float*)d_in[0];
    const float* emb   = (const float*)d_in[1];
    const float* inW1  = (const float*)d_in[2];
    const float* inb1  = (const float*)d_in[3];
    const float* ing1  = (const float*)d_in[4];
    const float* inbt1 = (const float*)d_in[5];
    const float* inW2  = (const float*)d_in[6];
    const float* inb2  = (const float*)d_in[7];
    const float* ing2  = (const float*)d_in[8];
    const float* inbt2 = (const float*)d_in[9];
    const float* cW1   = (const float*)d_in[10];
    const float* cb1   = (const float*)d_in[11];
    const float* cg1   = (const float*)d_in[12];
    const float* cbt1  = (const float*)d_in[13];
    const float* cW2   = (const float*)d_in[14];
    const float* cb2   = (const float*)d_in[15];
    const float* cg2   = (const float*)d_in[16];
    const float* cbt2  = (const float*)d_in[17];
    const float* ceps  = (const float*)d_in[18];
    const float* lng   = (const float*)d_in[19];
    const float* lnb   = (const float*)d_in[20];
    const float* outW  = (const float*)d_in[21];
    const float* outb  = (const float*)d_in[22];
    const int*   ecat  = (const int*)d_in[25];

    float* ws     = (float*)d_ws;
    unsigned* nep = (unsigned*)ws;              // 4096 u32 (16 KB bf16 ne)
    unsigned* catp = (unsigned*)(ws + 4096);    // 64*256 u32 (64 KB)
    float* hA   = ws + 4096 + 16384;            // B*N*HID
    float* hB   = hA + BB * NN * HID;
    float* out  = (float*)d_out;

    k_setup<<<328, 512, 0, stream>>>(x, emb, inW1, inb1, ing1, inbt1,
                                     inW2, inb2, ing2, inbt2, ecat, nep, catp, hA);

    for (int l = 0; l < 4; ++l) {
        const float* ho = (l & 1) ? hB : hA;
        float*       hn = (l & 1) ? hA : hB;
        k_layer<<<512, 512, 0, stream>>>(
            ho, hn, (const uint4*)nep, catp,
            cW1 + l * HID * HID, cb1 + l * HID, cg1 + l * HID, cbt1 + l * HID,
            cW2 + l * HID * HID, cb2 + l * HID, cg2 + l * HID, cbt2 + l * HID,
            ceps + l, lng + l * HID, lnb + l * HID,
            outW, outb, out, (l == 3) ? 1 : 0);
    }
}